// Round 5
// baseline (447.733 us; speedup 1.0000x reference)
//
#include <hip/hip_runtime.h>

#define N_NODES 100000
#define N_EDGES 1600000
#define D_FEAT 32

#define BSH 9                 // bucket = dst >> 9  (512 nodes per bucket)
#define BMASK 511
#define NB 196                // ceil(100000/512)
#define CAPB 9216             // per-bucket region capacity (mean 8192, sigma~90)

#define P1_BS 512
#define P1_TILE 4096          // 8 edges/thread
#define P1_CAP 64             // staging per bucket per block (mean ~21)

// ws layout (4-byte words):
//   cursorA [256]        int    per-bucket fill cursors (init to b*CAPB)
//   dinv    [N_NODES]    float
//   pairs   [NB*CAPB]    int    packed (src<<9)|(dst&511), bucket-grouped

__global__ void init_kernel(int* __restrict__ cursorA) {
    int b = blockIdx.x * blockDim.x + threadIdx.x;
    if (b < NB) cursorA[b] = b * CAPB;
}

// Pass 1: bucket edges by dst>>9 with LDS staging -> coalesced runs into
// fixed per-bucket regions (no scan needed).
__global__ void __launch_bounds__(P1_BS)
bucket_kernel(const int* __restrict__ edge_src,
              const int* __restrict__ edge_dst,
              int* __restrict__ cursorA,
              int* __restrict__ pairs, int n_edges) {
    __shared__ int s_cnt[NB];
    __shared__ int s_base[NB];
    __shared__ int s_off[NB + 1];
    __shared__ int s_buf[NB * P1_CAP];   // 196*64*4 = 50 KB

    int tile = blockIdx.x * P1_TILE;
    if (tile >= n_edges) return;

    for (int b = threadIdx.x; b < NB; b += P1_BS) s_cnt[b] = 0;
    __syncthreads();

    #pragma unroll
    for (int j = 0; j < P1_TILE / P1_BS; ++j) {
        int i = tile + j * P1_BS + threadIdx.x;
        if (i < n_edges) {
            int src = edge_src[i];
            int dst = edge_dst[i];
            int b = dst >> BSH;
            int packed = (src << BSH) | (dst & BMASK);
            int p = atomicAdd(&s_cnt[b], 1);
            if (p < P1_CAP) {
                s_buf[b * P1_CAP + p] = packed;
            } else {
                int gp = atomicAdd(&cursorA[b], 1);   // rare overflow path
                pairs[gp] = packed;
            }
        }
    }
    __syncthreads();

    for (int b = threadIdx.x; b < NB; b += P1_BS) {
        int c = min(s_cnt[b], P1_CAP);
        s_base[b] = atomicAdd(&cursorA[b], c);
        s_cnt[b] = c;
    }
    __syncthreads();
    if (threadIdx.x == 0) {
        int acc = 0;
        for (int b = 0; b < NB; ++b) { s_off[b] = acc; acc += s_cnt[b]; }
        s_off[NB] = acc;
    }
    __syncthreads();

    int total = s_off[NB];
    for (int t = threadIdx.x; t < total; t += P1_BS) {
        int lo = 0, hi = NB;
        while (hi - lo > 1) {
            int mid = (lo + hi) >> 1;
            if (t >= s_off[mid]) lo = mid; else hi = mid;
        }
        int idx = t - s_off[lo];
        pairs[s_base[lo] + idx] = s_buf[lo * P1_CAP + idx];
    }
}

// Per-bucket LDS histogram -> dinv (replaces global count atomics)
__global__ void hist_kernel(const int* __restrict__ pairs,
                            const int* __restrict__ cursorA,
                            float* __restrict__ dinv) {
    __shared__ int hist[512];
    int b = blockIdx.x;
    for (int i = threadIdx.x; i < 512; i += blockDim.x) hist[i] = 0;
    __syncthreads();
    int base = b * CAPB;
    int cnt = min(cursorA[b] - base, CAPB);
    for (int i = threadIdx.x; i < cnt; i += blockDim.x)
        atomicAdd(&hist[pairs[base + i] & BMASK], 1);
    __syncthreads();
    for (int i = threadIdx.x; i < 512; i += blockDim.x) {
        int node = (b << BSH) + i;
        if (node < N_NODES)
            dinv[node] = rsqrtf(fmaxf((float)hist[i], 1.0f));
    }
}

// One workgroup per bucket: accumulate agg for 512 nodes in LDS via
// float LDS atomics (XOR-swizzled), then fused Bernstein epilogue.
__global__ void __launch_bounds__(512)
agg_kernel(const float* __restrict__ feat,
           const int* __restrict__ pairs,
           const int* __restrict__ cursorA,
           const float* __restrict__ dinv,
           float* __restrict__ out) {
    __shared__ float agg_s[512 * 32];   // 64 KB
    int b = blockIdx.x;
    for (int i = threadIdx.x; i < 512 * 32; i += 512) agg_s[i] = 0.0f;
    __syncthreads();

    int base = b * CAPB;
    int cnt = min(cursorA[b] - base, CAPB);
    const float4* feat4 = reinterpret_cast<const float4*>(feat);

    int g = threadIdx.x >> 3;   // edge slot 0..63
    int j = threadIdx.x & 7;    // feature quad 0..7

    for (int e0 = 0; e0 < cnt; e0 += 256) {
        int i0 = e0 + g, i1 = i0 + 64, i2 = i0 + 128, i3 = i0 + 192;
        int p0 = (i0 < cnt) ? pairs[base + i0] : -1;
        int p1 = (i1 < cnt) ? pairs[base + i1] : -1;
        int p2 = (i2 < cnt) ? pairs[base + i2] : -1;
        int p3 = (i3 < cnt) ? pairs[base + i3] : -1;
        int d0 = 0, d1 = 0, d2 = 0, d3 = 0;
        float v0 = 0.f, v1 = 0.f, v2 = 0.f, v3 = 0.f;
        float4 f0, f1, f2, f3;
        if (p0 >= 0) { d0 = p0 & BMASK; int s = p0 >> BSH; v0 = dinv[s]; f0 = feat4[s * 8 + j]; }
        if (p1 >= 0) { d1 = p1 & BMASK; int s = p1 >> BSH; v1 = dinv[s]; f1 = feat4[s * 8 + j]; }
        if (p2 >= 0) { d2 = p2 & BMASK; int s = p2 >> BSH; v2 = dinv[s]; f2 = feat4[s * 8 + j]; }
        if (p3 >= 0) { d3 = p3 & BMASK; int s = p3 >> BSH; v3 = dinv[s]; f3 = feat4[s * 8 + j]; }
        int fb = 4 * j;
        if (p0 >= 0) {
            int rb = d0 << 5, sw = d0 & 31;
            atomicAdd(&agg_s[rb + ((fb + 0) ^ sw)], f0.x * v0);
            atomicAdd(&agg_s[rb + ((fb + 1) ^ sw)], f0.y * v0);
            atomicAdd(&agg_s[rb + ((fb + 2) ^ sw)], f0.z * v0);
            atomicAdd(&agg_s[rb + ((fb + 3) ^ sw)], f0.w * v0);
        }
        if (p1 >= 0) {
            int rb = d1 << 5, sw = d1 & 31;
            atomicAdd(&agg_s[rb + ((fb + 0) ^ sw)], f1.x * v1);
            atomicAdd(&agg_s[rb + ((fb + 1) ^ sw)], f1.y * v1);
            atomicAdd(&agg_s[rb + ((fb + 2) ^ sw)], f1.z * v1);
            atomicAdd(&agg_s[rb + ((fb + 3) ^ sw)], f1.w * v1);
        }
        if (p2 >= 0) {
            int rb = d2 << 5, sw = d2 & 31;
            atomicAdd(&agg_s[rb + ((fb + 0) ^ sw)], f2.x * v2);
            atomicAdd(&agg_s[rb + ((fb + 1) ^ sw)], f2.y * v2);
            atomicAdd(&agg_s[rb + ((fb + 2) ^ sw)], f2.z * v2);
            atomicAdd(&agg_s[rb + ((fb + 3) ^ sw)], f2.w * v2);
        }
        if (p3 >= 0) {
            int rb = d3 << 5, sw = d3 & 31;
            atomicAdd(&agg_s[rb + ((fb + 0) ^ sw)], f3.x * v3);
            atomicAdd(&agg_s[rb + ((fb + 1) ^ sw)], f3.y * v3);
            atomicAdd(&agg_s[rb + ((fb + 2) ^ sw)], f3.z * v3);
            atomicAdd(&agg_s[rb + ((fb + 3) ^ sw)], f3.w * v3);
        }
    }
    __syncthreads();

    // Fused epilogue: out = 2*y*(feat - y), y = 0.5*(feat - agg*dinv)
    float4* out4 = reinterpret_cast<float4*>(out);
    for (int idx = threadIdx.x; idx < 512 * 8; idx += 512) {
        int nl = idx >> 3;
        int q = idx & 7;
        int node = (b << BSH) + nl;
        if (node >= N_NODES) continue;
        float dvn = dinv[node];
        float4 fv = feat4[node * 8 + q];
        int rb = nl << 5, sw = nl & 31;
        float ax = agg_s[rb + ((4 * q + 0) ^ sw)];
        float ay = agg_s[rb + ((4 * q + 1) ^ sw)];
        float az = agg_s[rb + ((4 * q + 2) ^ sw)];
        float aw = agg_s[rb + ((4 * q + 3) ^ sw)];
        float yx = 0.5f * (fv.x - ax * dvn);
        float yy = 0.5f * (fv.y - ay * dvn);
        float yz = 0.5f * (fv.z - az * dvn);
        float yw = 0.5f * (fv.w - aw * dvn);
        float4 o;
        o.x = 2.0f * yx * (fv.x - yx);
        o.y = 2.0f * yy * (fv.y - yy);
        o.z = 2.0f * yz * (fv.z - yz);
        o.w = 2.0f * yw * (fv.w - yw);
        out4[node * 8 + q] = o;
    }
}

extern "C" void kernel_launch(void* const* d_in, const int* in_sizes, int n_in,
                              void* d_out, int out_size, void* d_ws, size_t ws_size,
                              hipStream_t stream) {
    const float* feat = (const float*)d_in[0];
    const int* edge_src = (const int*)d_in[1];
    const int* edge_dst = (const int*)d_in[2];
    float* out = (float*)d_out;

    int* ws = (int*)d_ws;
    int* cursorA = ws;                       // 256 ints
    float* dinv  = (float*)(cursorA + 256);  // N_NODES floats
    int* pairs   = (int*)(dinv + N_NODES);   // NB*CAPB ints

    init_kernel<<<1, 256, 0, stream>>>(cursorA);
    {
        int blocks = (N_EDGES + P1_TILE - 1) / P1_TILE;   // 391
        bucket_kernel<<<blocks, P1_BS, 0, stream>>>(edge_src, edge_dst,
                                                    cursorA, pairs, N_EDGES);
    }
    hist_kernel<<<NB, 256, 0, stream>>>(pairs, cursorA, dinv);
    agg_kernel<<<NB, 512, 0, stream>>>(feat, pairs, cursorA, dinv, out);
}

// Round 6
// 140.235 us; speedup vs baseline: 3.1927x; 3.1927x over previous
//
#include <hip/hip_runtime.h>

#define N_NODES 100000
#define N_EDGES 1600000
#define D_FEAT 32

#define BSH 8                 // bucket = dst >> 8  (256 nodes per bucket)
#define BMASK 255
#define NB 391                // ceil(100000/256)
#define CAPB 4864             // per-bucket capacity (mean 4096, sigma~64 -> 12 sigma)

#define P1_BS 512
#define P1_TILE 4096          // 8 edges/thread
#define P1_CAP 32             // staging per bucket per block (mean ~10.5)

// ws layout (4-byte words):
//   cursorA [512]        int    per-bucket fill cursors (init to b*CAPB)
//   start   [N_NODES]    int    CSR start (into padded ssrc)
//   end     [N_NODES]    int    CSR end
//   dinv    [N_NODES]    float
//   ssrc    [NB*CAPB]    int    srcs, dst-sorted within padded bucket regions
//   pairs   [NB*CAPB]    int    packed (src<<8)|(dst&255), bucket-grouped
//   sfeat   (alias pairs)float  feat*dinv[src]  (written after pairs dead)

__global__ void init_kernel(int* __restrict__ cursorA) {
    int b = blockIdx.x * blockDim.x + threadIdx.x;
    if (b < NB) cursorA[b] = b * CAPB;
}

// Pass 1: bucket edges by dst>>8 with LDS staging -> coalesced runs into
// fixed per-bucket regions.
__global__ void __launch_bounds__(P1_BS)
bucket_kernel(const int* __restrict__ edge_src,
              const int* __restrict__ edge_dst,
              int* __restrict__ cursorA,
              int* __restrict__ pairs, int n_edges) {
    __shared__ int s_cnt[NB];
    __shared__ int s_base[NB];
    __shared__ int s_off[NB + 1];
    __shared__ int s_buf[NB * P1_CAP];   // 391*32*4 = 50 KB

    int tile = blockIdx.x * P1_TILE;
    if (tile >= n_edges) return;

    for (int b = threadIdx.x; b < NB; b += P1_BS) s_cnt[b] = 0;
    __syncthreads();

    const int4* src4 = reinterpret_cast<const int4*>(edge_src);
    const int4* dst4 = reinterpret_cast<const int4*>(edge_dst);
    int tileq = blockIdx.x * (P1_TILE / 4);
    #pragma unroll
    for (int j = 0; j < P1_TILE / 4 / P1_BS; ++j) {
        int iq = tileq + j * P1_BS + threadIdx.x;
        if (iq * 4 < n_edges) {
            int4 sv = src4[iq];
            int4 dv = dst4[iq];
            int ss[4] = {sv.x, sv.y, sv.z, sv.w};
            int dd[4] = {dv.x, dv.y, dv.z, dv.w};
            #pragma unroll
            for (int u = 0; u < 4; ++u) {
                int b = dd[u] >> BSH;
                int packed = (ss[u] << BSH) | (dd[u] & BMASK);
                int p = atomicAdd(&s_cnt[b], 1);
                if (p < P1_CAP) {
                    s_buf[b * P1_CAP + p] = packed;
                } else {
                    int gp = atomicAdd(&cursorA[b], 1);   // rare overflow
                    pairs[gp] = packed;
                }
            }
        }
    }
    __syncthreads();

    for (int b = threadIdx.x; b < NB; b += P1_BS) {
        int c = min(s_cnt[b], P1_CAP);
        s_base[b] = atomicAdd(&cursorA[b], c);
        s_cnt[b] = c;
    }
    __syncthreads();
    if (threadIdx.x == 0) {
        int acc = 0;
        for (int b = 0; b < NB; ++b) { s_off[b] = acc; acc += s_cnt[b]; }
        s_off[NB] = acc;
    }
    __syncthreads();

    int total = s_off[NB];
    for (int t = threadIdx.x; t < total; t += P1_BS) {
        int lo = 0, hi = NB;
        while (hi - lo > 1) {
            int mid = (lo + hi) >> 1;
            if (t >= s_off[mid]) lo = mid; else hi = mid;
        }
        int idx = t - s_off[lo];
        pairs[s_base[lo] + idx] = s_buf[lo * P1_CAP + idx];
    }
}

// Pass 2: one WG per bucket — LDS counting sort by dst.
// Produces dst-sorted ssrc (coalesced write), CSR start/end, and dinv.
__global__ void __launch_bounds__(256)
sort_kernel(const int* __restrict__ pairs,
            const int* __restrict__ cursorA,
            int* __restrict__ ssrc,
            int* __restrict__ start,
            int* __restrict__ endv,
            float* __restrict__ dinv) {
    __shared__ int buf[CAPB];     // 19 KB
    __shared__ int outb[CAPB];    // 19 KB
    __shared__ int h[256];
    __shared__ int sc[256];
    __shared__ int cur[256];

    int b = blockIdx.x;
    int t = threadIdx.x;
    int base = b * CAPB;
    int cnt = min(cursorA[b] - base, CAPB);

    h[t] = 0;
    __syncthreads();
    for (int i = t; i < cnt; i += 256) {
        int p = pairs[base + i];
        buf[i] = p;
        atomicAdd(&h[p & BMASK], 1);
    }
    __syncthreads();

    // exclusive scan of h
    int v = h[t];
    sc[t] = v;
    __syncthreads();
    for (int off = 1; off < 256; off <<= 1) {
        int x = (t >= off) ? sc[t - off] : 0;
        __syncthreads();
        sc[t] += x;
        __syncthreads();
    }
    int ex = sc[t] - v;
    cur[t] = ex;
    int node = (b << BSH) + t;
    if (node < N_NODES) {
        start[node] = base + ex;
        endv[node] = base + ex + v;
        dinv[node] = rsqrtf(fmaxf((float)v, 1.0f));
    }
    __syncthreads();

    for (int i = t; i < cnt; i += 256) {
        int p = buf[i];
        int pos = atomicAdd(&cur[p & BMASK], 1);
        outb[pos] = p >> BSH;
    }
    __syncthreads();
    for (int i = t; i < cnt; i += 256)
        ssrc[base + i] = outb[i];
}

// sfeat[n] = feat[n] * dinv[n]  (streaming)
__global__ void sf_kernel(const float* __restrict__ feat,
                          const float* __restrict__ dinv,
                          float* __restrict__ sfeat) {
    int gid = blockIdx.x * blockDim.x + threadIdx.x;
    int total = N_NODES * 8;
    if (gid < total) {
        float dv = dinv[gid >> 3];
        float4 fv = reinterpret_cast<const float4*>(feat)[gid];
        fv.x *= dv; fv.y *= dv; fv.z *= dv; fv.w *= dv;
        reinterpret_cast<float4*>(sfeat)[gid] = fv;
    }
}

// Gather over pre-scaled features; fused Bernstein epilogue.
__global__ void gather_sf_kernel(const float* __restrict__ feat,
                                 const float* __restrict__ sfeat,
                                 const int* __restrict__ start,
                                 const int* __restrict__ endv,
                                 const int* __restrict__ ssrc,
                                 const float* __restrict__ dinv,
                                 float* __restrict__ out) {
    int gid = blockIdx.x * blockDim.x + threadIdx.x;
    int node = gid >> 3;
    int fq = gid & 7;
    if (node >= N_NODES) return;
    int k = start[node];
    int en = endv[node];
    const float4* sf4 = reinterpret_cast<const float4*>(sfeat);
    float4 acc = make_float4(0.f, 0.f, 0.f, 0.f);
    for (; k + 3 < en; k += 4) {
        int s0 = ssrc[k],     s1 = ssrc[k + 1];
        int s2 = ssrc[k + 2], s3 = ssrc[k + 3];
        float4 f0 = sf4[s0 * 8 + fq];
        float4 f1 = sf4[s1 * 8 + fq];
        float4 f2 = sf4[s2 * 8 + fq];
        float4 f3 = sf4[s3 * 8 + fq];
        acc.x += f0.x + f1.x + f2.x + f3.x;
        acc.y += f0.y + f1.y + f2.y + f3.y;
        acc.z += f0.z + f1.z + f2.z + f3.z;
        acc.w += f0.w + f1.w + f2.w + f3.w;
    }
    for (; k < en; ++k) {
        int s = ssrc[k];
        float4 fv = sf4[s * 8 + fq];
        acc.x += fv.x; acc.y += fv.y; acc.z += fv.z; acc.w += fv.w;
    }
    float dvn = dinv[node];
    float4 fv = reinterpret_cast<const float4*>(feat)[node * 8 + fq];
    float4 o;
    float yx = 0.5f * (fv.x - acc.x * dvn);
    float yy = 0.5f * (fv.y - acc.y * dvn);
    float yz = 0.5f * (fv.z - acc.z * dvn);
    float yw = 0.5f * (fv.w - acc.w * dvn);
    o.x = 2.0f * yx * (fv.x - yx);
    o.y = 2.0f * yy * (fv.y - yy);
    o.z = 2.0f * yz * (fv.z - yz);
    o.w = 2.0f * yw * (fv.w - yw);
    reinterpret_cast<float4*>(out)[gid] = o;
}

// Fallback gather without sfeat (if ws too small): dinv gathered per edge.
__global__ void gather_kernel(const float* __restrict__ feat,
                              const int* __restrict__ start,
                              const int* __restrict__ endv,
                              const int* __restrict__ ssrc,
                              const float* __restrict__ dinv,
                              float* __restrict__ out) {
    int gid = blockIdx.x * blockDim.x + threadIdx.x;
    int node = gid >> 3;
    int fq = gid & 7;
    if (node >= N_NODES) return;
    int k = start[node];
    int en = endv[node];
    const float4* feat4 = reinterpret_cast<const float4*>(feat);
    float4 acc = make_float4(0.f, 0.f, 0.f, 0.f);
    for (; k < en; ++k) {
        int s = ssrc[k];
        float dv = dinv[s];
        float4 fv = feat4[s * 8 + fq];
        acc.x += fv.x * dv; acc.y += fv.y * dv;
        acc.z += fv.z * dv; acc.w += fv.w * dv;
    }
    float dvn = dinv[node];
    float4 fv = feat4[node * 8 + fq];
    float4 o;
    float yx = 0.5f * (fv.x - acc.x * dvn);
    float yy = 0.5f * (fv.y - acc.y * dvn);
    float yz = 0.5f * (fv.z - acc.z * dvn);
    float yw = 0.5f * (fv.w - acc.w * dvn);
    o.x = 2.0f * yx * (fv.x - yx);
    o.y = 2.0f * yy * (fv.y - yy);
    o.z = 2.0f * yz * (fv.z - yz);
    o.w = 2.0f * yw * (fv.w - yw);
    reinterpret_cast<float4*>(out)[gid] = o;
}

extern "C" void kernel_launch(void* const* d_in, const int* in_sizes, int n_in,
                              void* d_out, int out_size, void* d_ws, size_t ws_size,
                              hipStream_t stream) {
    const float* feat = (const float*)d_in[0];
    const int* edge_src = (const int*)d_in[1];
    const int* edge_dst = (const int*)d_in[2];
    float* out = (float*)d_out;

    int* ws = (int*)d_ws;
    int* cursorA = ws;                          // 512
    int* start   = cursorA + 512;               // N_NODES
    int* endv    = start + N_NODES;             // N_NODES
    float* dinv  = (float*)(endv + N_NODES);    // N_NODES
    int* ssrc    = (int*)(dinv + N_NODES);      // NB*CAPB
    int* pairs   = ssrc + NB * CAPB;            // NB*CAPB
    float* sfeat = (float*)pairs;               // N_NODES*32, aliases pairs

    size_t need_sf = ((size_t)(512 + 3 * N_NODES + NB * CAPB) +
                      (size_t)N_NODES * D_FEAT) * 4;
    bool use_sf = ws_size >= need_sf;

    init_kernel<<<1, 512, 0, stream>>>(cursorA);
    {
        int blocks = (N_EDGES + P1_TILE - 1) / P1_TILE;   // 391
        bucket_kernel<<<blocks, P1_BS, 0, stream>>>(edge_src, edge_dst,
                                                    cursorA, pairs, N_EDGES);
    }
    sort_kernel<<<NB, 256, 0, stream>>>(pairs, cursorA, ssrc, start, endv, dinv);
    int total = N_NODES * 8;
    int blocks = (total + 255) / 256;
    if (use_sf) {
        sf_kernel<<<blocks, 256, 0, stream>>>(feat, dinv, sfeat);
        gather_sf_kernel<<<blocks, 256, 0, stream>>>(feat, sfeat, start, endv,
                                                     ssrc, dinv, out);
    } else {
        gather_kernel<<<blocks, 256, 0, stream>>>(feat, start, endv,
                                                  ssrc, dinv, out);
    }
}